// Round 5
// baseline (151.007 us; speedup 1.0000x reference)
//
#include <hip/hip_runtime.h>
#include <stdint.h>

static constexpr int P       = 24;
static constexpr int EMB_D   = 32;
static constexpr int N_AC    = 38;
static constexpr int N_AT    = 6;
static constexpr int N_RC    = 21;
static constexpr int MAXSEQ  = 1024;
static constexpr int VEC_OUT = 64;
static constexpr int SC_OUT  = 256;
static constexpr int FEAT    = 3 * VEC_OUT + SC_OUT;   // 448
static constexpr int CT      = N_AC * N_AT;            // 228
static constexpr int NROWS   = P * CT;                 // 5472
static constexpr int ROWB    = SC_OUT * 2;             // 512 B bf16 row
static constexpr uint32_t ZROWB = (uint32_t)NROWS * ROWB;  // zero row offset

__device__ __forceinline__ unsigned short f2bf(float f) {
    uint32_t x = __float_as_uint(f);
    uint32_t r = (x + 0x7FFFu + ((x >> 16) & 1u)) >> 16;  // RNE
    return (unsigned short)r;
}

// ---- K1: init bounds + build all four f32 partial tables -------------------
__global__ __launch_bounds__(256) void k1_init_build(
        const float* __restrict__ Wac, const float* __restrict__ Wat,
        const float* __restrict__ Wrc, const float* __restrict__ Wri,
        const float* __restrict__ Wsc,
        float* __restrict__ Ec, float* __restrict__ Et,
        float* __restrict__ Erc, float* __restrict__ Erix,
        int* __restrict__ starts, int* __restrict__ ends, int R) {
    int b = blockIdx.x;
    const int initB = (R + 255) / 256;
    if (b < initB) {
        int i = b * 256 + threadIdx.x;
        if (i < R) { starts[i] = 0; ends[i] = 0; }
        return;
    }
    b -= initB;
    const float* Wemb; float* E; int n_emb, sc_base, idx;
    if (b < P * N_AC) {
        Wemb = Wac; E = Ec; n_emb = N_AC; sc_base = 0; idx = b;
    } else if (b < P * N_AC + P * N_AT) {
        Wemb = Wat; E = Et; n_emb = N_AT; sc_base = P * EMB_D; idx = b - P * N_AC;
    } else if (b < P * N_AC + P * N_AT + N_RC) {
        Wemb = Wrc; E = Erc; n_emb = N_RC; sc_base = 2 * P * EMB_D;
        idx = b - (P * N_AC + P * N_AT);
    } else {
        Wemb = Wri; E = Erix; n_emb = MAXSEQ; sc_base = 2 * P * EMB_D + EMB_D;
        idx = b - (P * N_AC + P * N_AT + N_RC);
    }
    int p = idx / n_emb, e = idx % n_emb;
    int o = threadIdx.x;
    const float* wrow = Wemb + (size_t)e * EMB_D;
    const float* scol = Wsc + (size_t)(sc_base + p * EMB_D) * SC_OUT + o;
    float s = 0.f;
#pragma unroll
    for (int d = 0; d < EMB_D; ++d) s += wrow[d] * scol[(size_t)d * SC_OUT];
    E[(size_t)idx * SC_OUT + o] = s * 0.025f;  // 1/sqrt(1600)
}

// ---- K2: residue run boundaries (ri sorted) --------------------------------
__global__ void k2_find_bounds(const int* __restrict__ ri, int* __restrict__ starts,
                               int* __restrict__ ends, int N) {
    int i = blockIdx.x * blockDim.x + threadIdx.x;
    if (i >= N) return;
    int r = ri[i];
    if (i == 0 || ri[i - 1] != r) starts[r] = i;
    if (i == N - 1 || ri[i + 1] != r) ends[r] = i + 1;
}

// ---- K3: fuse bf16 table + hdr + per-residue packed record -----------------
// rec[r][0..15]  = table row byte offsets for slots 0..15 (zero-row if pad)
// rec[r][16..63] = 48 rel floats (slot k xyz at lanes 16+3k..18+3k), 0 if pad
__global__ __launch_bounds__(256) void k3_fuse_prep(
        const float* __restrict__ Ec, const float* __restrict__ Et,
        unsigned short* __restrict__ Etab,
        const int* __restrict__ starts, const int* __restrict__ ends,
        const int* __restrict__ rcode, const int* __restrict__ rseq,
        const int* __restrict__ acode, const int* __restrict__ atype,
        const float* __restrict__ rel,
        int4* __restrict__ hdr, uint32_t* __restrict__ recArr, int R) {
    int b = blockIdx.x;
    if (b < NROWS + 1) {
        int o = threadIdx.x;
        if (b == NROWS) { Etab[(size_t)b * SC_OUT + o] = 0; return; }
        int j = b / CT, ct = b % CT, c = ct / N_AT, t = ct % N_AT;
        float s = Ec[((size_t)j * N_AC + c) * SC_OUT + o] +
                  Et[((size_t)j * N_AT + t) * SC_OUT + o];
        Etab[(size_t)b * SC_OUT + o] = f2bf(s);
        return;
    }
    b -= NROWS + 1;
    const int hdrB = (R + 255) >> 8;
    if (b < hdrB) {
        int i = b * 256 + threadIdx.x;
        if (i < R) {
            int st = starts[i];
            int c = ends[i] - st; if (c > P) c = P;
            hdr[i] = make_int4(st, c, rcode[i], rseq[i]);
        }
        return;
    }
    b -= hdrB;
    int i = b * 256 + threadIdx.x;
    if (i >= R * 64) return;
    int r = i >> 6, l = i & 63;
    int st = starts[r];
    int c = ends[r] - st; if (c > P) c = P;
    uint32_t out;
    if (l < 16) {
        out = ZROWB;
        if (l < c)
            out = (uint32_t)((l * CT + acode[st + l] * N_AT + atype[st + l]) * ROWB);
    } else {
        int idx = l - 16, k = idx / 3, cc = idx - k * 3;
        float v = 0.f;
        if (k < c) v = rel[(size_t)(st + k) * 3 + cc];
        out = __float_as_uint(v);
    }
    recArr[(size_t)r * 64 + l] = out;
}

// ---- K4: persistent waves, 3-stage software pipeline -----------------------
__global__ __launch_bounds__(256, 4) void k4_residue(
        const float* __restrict__ base, const int4* __restrict__ hdr,
        const uint32_t* __restrict__ recArr,
        const unsigned char* __restrict__ tab,
        const float* __restrict__ Erc, const float* __restrict__ Erix,
        const float* __restrict__ Wvec,
        const int* __restrict__ acode, const int* __restrict__ atype,
        const float* __restrict__ rel,
        float* __restrict__ out_coords, float* __restrict__ out_feat, int R) {

    const int wave   = (blockIdx.x << 2) + (threadIdx.x >> 6);
    const int lane   = threadIdx.x & 63;
    const int lb     = lane * 8;
    const int lane4  = lane * 4;
    const int totalw = gridDim.x << 2;
    const int NJ = (R + totalw - 1) / totalw;
    const int J6 = (NJ / 6) * 6;

    float w[16];
#pragma unroll
    for (int k = 0; k < 16; ++k) w[k] = Wvec[k * VEC_OUT + lane];

    uint32_t rec0, rec1, rec2;
    int4 h0, h1, h2;
    uint2 gA[16], gB[16];
    float4 eaA, ebA, eaB, ebB;

    auto RAW = [&](uint32_t& RB, int4& HB, int jj) {
        int rr = wave + jj * totalw;
        rr = rr < R ? rr : R - 1;
        HB = hdr[rr];
        RB = recArr[(size_t)rr * 64 + lane];
    };
    auto GATHER = [&](uint2 (&G)[16], float4& EA, float4& EB,
                      uint32_t RB, const int4& HB) {
#pragma unroll
        for (int k = 0; k < 16; ++k) {
            uint32_t ro = (uint32_t)__builtin_amdgcn_readlane((int)RB, k);
            G[k] = *reinterpret_cast<const uint2*>(tab + ro + lb);
        }
        EA = *reinterpret_cast<const float4*>(Erc + (size_t)HB.z * SC_OUT + lane4);
        EB = *reinterpret_cast<const float4*>(Erix + (size_t)HB.w * SC_OUT + lane4);
    };
    auto ACC = [&](const uint2 (&G)[16], const float4& EA, const float4& EB,
                   uint32_t RB, const int4& HB, int jj) {
        int rr = wave + jj * totalw;
        if (rr >= R) return;
        float a0 = EA.x + EB.x, a1 = EA.y + EB.y;
        float a2 = EA.z + EB.z, a3 = EA.w + EB.w;
        float v0 = 0.f, v1 = 0.f, v2 = 0.f;
#pragma unroll
        for (int k = 0; k < 16; ++k) {
            a0 += __uint_as_float(G[k].x << 16);
            a1 += __uint_as_float(G[k].x & 0xFFFF0000u);
            a2 += __uint_as_float(G[k].y << 16);
            a3 += __uint_as_float(G[k].y & 0xFFFF0000u);
            float sx = __uint_as_float((uint32_t)__builtin_amdgcn_readlane((int)RB, 16 + 3 * k));
            float sy = __uint_as_float((uint32_t)__builtin_amdgcn_readlane((int)RB, 17 + 3 * k));
            float sz = __uint_as_float((uint32_t)__builtin_amdgcn_readlane((int)RB, 18 + 3 * k));
            v0 = fmaf(sx, w[k], v0);
            v1 = fmaf(sy, w[k], v1);
            v2 = fmaf(sz, w[k], v2);
        }
        int cnt = HB.y;
        if (cnt > 16) {                         // cold generic tail
            int st = HB.x;
            for (int k = 16; k < cnt; ++k) {
                int c = acode[st + k], t = atype[st + k];
                uint32_t ro = (uint32_t)((k * CT + c * N_AT + t) * ROWB);
                uint2 gg = *reinterpret_cast<const uint2*>(tab + ro + lb);
                float ww = Wvec[k * VEC_OUT + lane];
                a0 += __uint_as_float(gg.x << 16);
                a1 += __uint_as_float(gg.x & 0xFFFF0000u);
                a2 += __uint_as_float(gg.y << 16);
                a3 += __uint_as_float(gg.y & 0xFFFF0000u);
                float sx = rel[(size_t)(st + k) * 3];
                float sy = rel[(size_t)(st + k) * 3 + 1];
                float sz = rel[(size_t)(st + k) * 3 + 2];
                v0 = fmaf(sx, ww, v0);
                v1 = fmaf(sy, ww, v1);
                v2 = fmaf(sz, ww, v2);
            }
        }
        const float vs = 0.20412414523193150818f;  // 1/sqrt(24)
        float* frow = out_feat + (size_t)rr * FEAT;
        frow[lane * 3 + 0] = v0 * vs;
        frow[lane * 3 + 1] = v1 * vs;
        frow[lane * 3 + 2] = v2 * vs;
        *reinterpret_cast<float4*>(frow + 3 * VEC_OUT + lane4) =
            make_float4(a0, a1, a2, a3);
        if (lane < 3) out_coords[(size_t)rr * 3 + lane] = base[(size_t)rr * 3 + lane];
    };

    // prologue
    RAW(rec0, h0, 0);
    RAW(rec1, h1, 1);
    GATHER(gA, eaA, ebA, rec0, h0);

    // steady-state: slot s = { RAW(s+2), GATHER(s+1), ACC(s) }, unroll 6
    for (int s = 0; s < J6; s += 6) {
        RAW(rec2, h2, s + 2); GATHER(gB, eaB, ebB, rec1, h1); ACC(gA, eaA, ebA, rec0, h0, s + 0);
        RAW(rec0, h0, s + 3); GATHER(gA, eaA, ebA, rec2, h2); ACC(gB, eaB, ebB, rec1, h1, s + 1);
        RAW(rec1, h1, s + 4); GATHER(gB, eaB, ebB, rec0, h0); ACC(gA, eaA, ebA, rec2, h2, s + 2);
        RAW(rec2, h2, s + 5); GATHER(gA, eaA, ebA, rec1, h1); ACC(gB, eaB, ebB, rec0, h0, s + 3);
        RAW(rec0, h0, s + 6); GATHER(gB, eaB, ebB, rec2, h2); ACC(gA, eaA, ebA, rec1, h1, s + 4);
        RAW(rec1, h1, s + 7); GATHER(gA, eaA, ebA, rec0, h0); ACC(gB, eaB, ebB, rec2, h2, s + 5);
    }
    // serial cleanup for the last NJ - J6 residues (<= 5)
    for (int j = J6; j < NJ; ++j) {
        RAW(rec0, h0, j);
        GATHER(gA, eaA, ebA, rec0, h0);
        ACC(gA, eaA, ebA, rec0, h0, j);
    }
}

extern "C" void kernel_launch(void* const* d_in, const int* in_sizes, int n_in,
                              void* d_out, int out_size, void* d_ws, size_t ws_size,
                              hipStream_t stream) {
    const float* base  = (const float*)d_in[0];
    const float* rel   = (const float*)d_in[1];
    const int*   rcode = (const int*)d_in[2];
    const int*   rseq  = (const int*)d_in[3];
    const int*   acode = (const int*)d_in[4];
    const int*   atype = (const int*)d_in[5];
    const int*   ri    = (const int*)d_in[6];
    const float* Wac   = (const float*)d_in[7];
    const float* Wat   = (const float*)d_in[8];
    const float* Wrc   = (const float*)d_in[9];
    const float* Wri   = (const float*)d_in[10];
    const float* Wv    = (const float*)d_in[11];
    const float* Wsc   = (const float*)d_in[12];

    const int R = in_sizes[0] / 3;
    const int N = in_sizes[6];

    float* out_coords = (float*)d_out;
    float* out_feat   = out_coords + (size_t)R * 3;

    char* ws = (char*)d_ws;
    size_t ofs = 0;
    auto alloc = [&](size_t bytes) {
        void* p = ws + ofs;
        ofs = (ofs + bytes + 255) & ~255ULL;
        return p;
    };
    int*            starts = (int*)alloc((size_t)R * 4);
    int*            ends   = (int*)alloc((size_t)R * 4);
    float*          Ec_f   = (float*)alloc((size_t)P * N_AC * SC_OUT * 4);
    float*          Et_f   = (float*)alloc((size_t)P * N_AT * SC_OUT * 4);
    float*          Erc_f  = (float*)alloc((size_t)N_RC * SC_OUT * 4);
    float*          Erix_f = (float*)alloc((size_t)MAXSEQ * SC_OUT * 4);
    unsigned short* Etab   = (unsigned short*)alloc((size_t)(NROWS + 1) * SC_OUT * 2);
    int4*           hdr    = (int4*)alloc((size_t)R * 16);
    uint32_t*       recArr = (uint32_t*)alloc((size_t)R * 64 * 4);
    (void)ws_size; (void)n_in; (void)out_size;

    const int initB = (R + 255) / 256;
    const int k1B   = initB + P * N_AC + P * N_AT + N_RC + MAXSEQ;
    const int hdrB  = (R + 255) / 256;
    const int recB  = (R * 64 + 255) / 256;
    const int k3B   = (NROWS + 1) + hdrB + recB;

    k1_init_build<<<k1B, 256, 0, stream>>>(Wac, Wat, Wrc, Wri, Wsc,
                                           Ec_f, Et_f, Erc_f, Erix_f, starts, ends, R);
    k2_find_bounds<<<(N + 255) / 256, 256, 0, stream>>>(ri, starts, ends, N);
    k3_fuse_prep<<<k3B, 256, 0, stream>>>(Ec_f, Et_f, Etab, starts, ends,
                                          rcode, rseq, acode, atype, rel, hdr, recArr, R);
    k4_residue<<<1024, 256, 0, stream>>>(
        base, hdr, recArr, (const unsigned char*)Etab,
        Erc_f, Erix_f, Wv, acode, atype, rel, out_coords, out_feat, R);
}

// Round 6
// 63.438 us; speedup vs baseline: 2.3804x; 2.3804x over previous
//
#include <hip/hip_runtime.h>
#include <stdint.h>

static constexpr int P       = 24;
static constexpr int EMB_D   = 32;
static constexpr int N_AC    = 38;
static constexpr int N_AT    = 6;
static constexpr int N_RC    = 21;
static constexpr int MAXSEQ  = 1024;
static constexpr int VEC_OUT = 64;
static constexpr int SC_OUT  = 256;
static constexpr int FEAT    = 3 * VEC_OUT + SC_OUT;   // 448
static constexpr int CT      = N_AC * N_AT;            // 228
static constexpr int NROWS   = P * CT;                 // 5472
static constexpr int ROWB    = SC_OUT * 2;             // 512 B bf16 row
static constexpr uint32_t ZROWB = (uint32_t)NROWS * ROWB;  // zero row offset

__device__ __forceinline__ unsigned short f2bf(float f) {
    uint32_t x = __float_as_uint(f);
    uint32_t r = (x + 0x7FFFu + ((x >> 16) & 1u)) >> 16;  // RNE
    return (unsigned short)r;
}

// ---- K1: init bounds + build all four f32 partial tables -------------------
__global__ __launch_bounds__(256) void k1_init_build(
        const float* __restrict__ Wac, const float* __restrict__ Wat,
        const float* __restrict__ Wrc, const float* __restrict__ Wri,
        const float* __restrict__ Wsc,
        float* __restrict__ Ec, float* __restrict__ Et,
        float* __restrict__ Erc, float* __restrict__ Erix,
        int* __restrict__ starts, int* __restrict__ ends, int R) {
    int b = blockIdx.x;
    const int initB = (R + 255) / 256;
    if (b < initB) {
        int i = b * 256 + threadIdx.x;
        if (i < R) { starts[i] = 0; ends[i] = 0; }
        return;
    }
    b -= initB;
    const float* Wemb; float* E; int n_emb, sc_base, idx;
    if (b < P * N_AC) {
        Wemb = Wac; E = Ec; n_emb = N_AC; sc_base = 0; idx = b;
    } else if (b < P * N_AC + P * N_AT) {
        Wemb = Wat; E = Et; n_emb = N_AT; sc_base = P * EMB_D; idx = b - P * N_AC;
    } else if (b < P * N_AC + P * N_AT + N_RC) {
        Wemb = Wrc; E = Erc; n_emb = N_RC; sc_base = 2 * P * EMB_D;
        idx = b - (P * N_AC + P * N_AT);
    } else {
        Wemb = Wri; E = Erix; n_emb = MAXSEQ; sc_base = 2 * P * EMB_D + EMB_D;
        idx = b - (P * N_AC + P * N_AT + N_RC);
    }
    int p = idx / n_emb, e = idx % n_emb;
    int o = threadIdx.x;
    const float* wrow = Wemb + (size_t)e * EMB_D;
    const float* scol = Wsc + (size_t)(sc_base + p * EMB_D) * SC_OUT + o;
    float s = 0.f;
#pragma unroll
    for (int d = 0; d < EMB_D; ++d) s += wrow[d] * scol[(size_t)d * SC_OUT];
    E[(size_t)idx * SC_OUT + o] = s * 0.025f;  // 1/sqrt(1600)
}

// ---- K2: residue run boundaries (ri sorted) --------------------------------
__global__ void k2_find_bounds(const int* __restrict__ ri, int* __restrict__ starts,
                               int* __restrict__ ends, int N) {
    int i = blockIdx.x * blockDim.x + threadIdx.x;
    if (i >= N) return;
    int r = ri[i];
    if (i == 0 || ri[i - 1] != r) starts[r] = i;
    if (i == N - 1 || ri[i + 1] != r) ends[r] = i + 1;
}

// ---- K3: fuse bf16 table + hdr + packed record + coords copy ---------------
// rec[r][0..15]  = table row byte offsets for slots 0..15 (zero-row if pad)
// rec[r][16..63] = 48 rel floats (slot k xyz at lanes 16+3k..18+3k), 0 if pad
__global__ __launch_bounds__(256) void k3_fuse_prep(
        const float* __restrict__ Ec, const float* __restrict__ Et,
        unsigned short* __restrict__ Etab,
        const int* __restrict__ starts, const int* __restrict__ ends,
        const int* __restrict__ rcode, const int* __restrict__ rseq,
        const int* __restrict__ acode, const int* __restrict__ atype,
        const float* __restrict__ rel, const float* __restrict__ base,
        float* __restrict__ out_coords,
        int4* __restrict__ hdr, uint32_t* __restrict__ recArr, int R) {
    int b = blockIdx.x;
    if (b < NROWS + 1) {
        int o = threadIdx.x;
        if (b == NROWS) { Etab[(size_t)b * SC_OUT + o] = 0; return; }
        int j = b / CT, ct = b % CT, c = ct / N_AT, t = ct % N_AT;
        float s = Ec[((size_t)j * N_AC + c) * SC_OUT + o] +
                  Et[((size_t)j * N_AT + t) * SC_OUT + o];
        Etab[(size_t)b * SC_OUT + o] = f2bf(s);
        return;
    }
    b -= NROWS + 1;
    const int hdrB = (R + 255) >> 8;
    if (b < hdrB) {
        int i = b * 256 + threadIdx.x;
        if (i < R) {
            int st = starts[i];
            int c = ends[i] - st; if (c > P) c = P;
            hdr[i] = make_int4(st, c, rcode[i], rseq[i]);
        }
        return;
    }
    b -= hdrB;
    const int coordB = (3 * R + 1023) >> 10;   // float4 copy, 1024 floats/block
    if (b < coordB) {
        int i = b * 256 + threadIdx.x;          // float4 index
        int n4 = (3 * R) >> 2;
        if (i < n4)
            reinterpret_cast<float4*>(out_coords)[i] =
                reinterpret_cast<const float4*>(base)[i];
        if (i == n4) {                          // scalar tail (3R % 4)
            for (int t = 4 * n4; t < 3 * R; ++t) out_coords[t] = base[t];
        }
        return;
    }
    b -= coordB;
    int i = b * 256 + threadIdx.x;
    if (i >= R * 64) return;
    int r = i >> 6, l = i & 63;
    int st = starts[r];
    int c = ends[r] - st; if (c > P) c = P;
    uint32_t out;
    if (l < 16) {
        out = ZROWB;
        if (l < c)
            out = (uint32_t)((l * CT + acode[st + l] * N_AT + atype[st + l]) * ROWB);
    } else {
        int idx = l - 16, k = idx / 3, cc = idx - k * 3;
        float v = 0.f;
        if (k < c) v = rel[(size_t)(st + k) * 3 + cc];
        out = __float_as_uint(v);
    }
    recArr[(size_t)r * 64 + l] = out;
}

// ---- K4: persistent waves, grid-stride, depth-1 prefetch -------------------
__global__ __launch_bounds__(256, 4) void k4_residue(
        const int4* __restrict__ hdr, const uint32_t* __restrict__ recArr,
        const unsigned char* __restrict__ tab,
        const float* __restrict__ Erc, const float* __restrict__ Erix,
        const float* __restrict__ Wvec,
        const int* __restrict__ acode, const int* __restrict__ atype,
        const float* __restrict__ rel,
        float* __restrict__ out_feat, int R) {

    const int wave   = (blockIdx.x << 2) + (threadIdx.x >> 6);
    const int lane   = threadIdx.x & 63;
    const int lb     = lane * 8;
    const int lane4  = lane * 4;
    const int totalw = gridDim.x << 2;
    if (wave >= R) return;

    float w[16];
#pragma unroll
    for (int k = 0; k < 16; ++k) w[k] = Wvec[k * VEC_OUT + lane];

    uint32_t recA, recB;
    int4 hA, hB;
    float4 eaA, ebA, eaB, ebB;

    auto PRE = [&](uint32_t& rec, int4& h, float4& ea, float4& eb, int j) {
        int rr = __builtin_amdgcn_readfirstlane(j < R ? j : R - 1);
        h   = hdr[rr];                                   // s_load_dwordx4
        rec = recArr[(size_t)rr * 64 + lane];            // coalesced vmem
        ea  = *reinterpret_cast<const float4*>(Erc + (size_t)h.z * SC_OUT + lane4);
        eb  = *reinterpret_cast<const float4*>(Erix + (size_t)h.w * SC_OUT + lane4);
    };

    auto BODY = [&](uint32_t rec, const int4& h, const float4& ea, const float4& eb,
                    uint32_t& recN, int4& hN, float4& eaN, float4& ebN, int j) {
        // 1) issue current residue's 16 table gathers (critical path first)
        uint2 g[16];
#pragma unroll
        for (int k = 0; k < 16; ++k) {
            uint32_t ro = (uint32_t)__builtin_amdgcn_readlane((int)rec, k);
            g[k] = *reinterpret_cast<const uint2*>(tab + ro + lb);
        }
        // 2) issue next residue's prefetch (covers its latency under ACC)
        PRE(recN, hN, eaN, ebN, j + totalw);
        // 3) accumulate
        float a0 = ea.x + eb.x, a1 = ea.y + eb.y;
        float a2 = ea.z + eb.z, a3 = ea.w + eb.w;
        float v0 = 0.f, v1 = 0.f, v2 = 0.f;
#pragma unroll
        for (int k = 0; k < 16; ++k) {
            a0 += __uint_as_float(g[k].x << 16);
            a1 += __uint_as_float(g[k].x & 0xFFFF0000u);
            a2 += __uint_as_float(g[k].y << 16);
            a3 += __uint_as_float(g[k].y & 0xFFFF0000u);
            float sx = __uint_as_float((uint32_t)__builtin_amdgcn_readlane((int)rec, 16 + 3 * k));
            float sy = __uint_as_float((uint32_t)__builtin_amdgcn_readlane((int)rec, 17 + 3 * k));
            float sz = __uint_as_float((uint32_t)__builtin_amdgcn_readlane((int)rec, 18 + 3 * k));
            v0 = fmaf(sx, w[k], v0);
            v1 = fmaf(sy, w[k], v1);
            v2 = fmaf(sz, w[k], v2);
        }
        if (h.y > 16) {                          // cold generic tail (APR<=16 skips)
            int st = h.x;
            for (int k = 16; k < h.y; ++k) {
                int c = acode[st + k], t = atype[st + k];
                uint32_t ro = (uint32_t)((k * CT + c * N_AT + t) * ROWB);
                uint2 gg = *reinterpret_cast<const uint2*>(tab + ro + lb);
                float ww = Wvec[k * VEC_OUT + lane];
                a0 += __uint_as_float(gg.x << 16);
                a1 += __uint_as_float(gg.x & 0xFFFF0000u);
                a2 += __uint_as_float(gg.y << 16);
                a3 += __uint_as_float(gg.y & 0xFFFF0000u);
                v0 = fmaf(rel[(size_t)(st + k) * 3], ww, v0);
                v1 = fmaf(rel[(size_t)(st + k) * 3 + 1], ww, v1);
                v2 = fmaf(rel[(size_t)(st + k) * 3 + 2], ww, v2);
            }
        }
        const float vs = 0.20412414523193150818f;  // 1/sqrt(24)
        float* frow = out_feat + (size_t)j * FEAT;
        frow[lane * 3 + 0] = v0 * vs;
        frow[lane * 3 + 1] = v1 * vs;
        frow[lane * 3 + 2] = v2 * vs;
        *reinterpret_cast<float4*>(frow + 3 * VEC_OUT + lane4) =
            make_float4(a0, a1, a2, a3);
    };

    PRE(recA, hA, eaA, ebA, wave);
    int j = wave;
    while (true) {
        BODY(recA, hA, eaA, ebA, recB, hB, eaB, ebB, j);
        j += totalw;
        if (j >= R) break;
        BODY(recB, hB, eaB, ebB, recA, hA, eaA, ebA, j);
        j += totalw;
        if (j >= R) break;
    }
}

extern "C" void kernel_launch(void* const* d_in, const int* in_sizes, int n_in,
                              void* d_out, int out_size, void* d_ws, size_t ws_size,
                              hipStream_t stream) {
    const float* base  = (const float*)d_in[0];
    const float* rel   = (const float*)d_in[1];
    const int*   rcode = (const int*)d_in[2];
    const int*   rseq  = (const int*)d_in[3];
    const int*   acode = (const int*)d_in[4];
    const int*   atype = (const int*)d_in[5];
    const int*   ri    = (const int*)d_in[6];
    const float* Wac   = (const float*)d_in[7];
    const float* Wat   = (const float*)d_in[8];
    const float* Wrc   = (const float*)d_in[9];
    const float* Wri   = (const float*)d_in[10];
    const float* Wv    = (const float*)d_in[11];
    const float* Wsc   = (const float*)d_in[12];

    const int R = in_sizes[0] / 3;
    const int N = in_sizes[6];

    float* out_coords = (float*)d_out;
    float* out_feat   = out_coords + (size_t)R * 3;

    char* ws = (char*)d_ws;
    size_t ofs = 0;
    auto alloc = [&](size_t bytes) {
        void* p = ws + ofs;
        ofs = (ofs + bytes + 255) & ~255ULL;
        return p;
    };
    int*            starts = (int*)alloc((size_t)R * 4);
    int*            ends   = (int*)alloc((size_t)R * 4);
    float*          Ec_f   = (float*)alloc((size_t)P * N_AC * SC_OUT * 4);
    float*          Et_f   = (float*)alloc((size_t)P * N_AT * SC_OUT * 4);
    float*          Erc_f  = (float*)alloc((size_t)N_RC * SC_OUT * 4);
    float*          Erix_f = (float*)alloc((size_t)MAXSEQ * SC_OUT * 4);
    unsigned short* Etab   = (unsigned short*)alloc((size_t)(NROWS + 1) * SC_OUT * 2);
    int4*           hdr    = (int4*)alloc((size_t)R * 16);
    uint32_t*       recArr = (uint32_t*)alloc((size_t)R * 64 * 4);
    (void)ws_size; (void)n_in; (void)out_size;

    const int initB  = (R + 255) / 256;
    const int k1B    = initB + P * N_AC + P * N_AT + N_RC + MAXSEQ;
    const int hdrB   = (R + 255) / 256;
    const int coordB = (3 * R + 1023) / 1024;
    const int recB   = (R * 64 + 255) / 256;
    const int k3B    = (NROWS + 1) + hdrB + coordB + recB;

    k1_init_build<<<k1B, 256, 0, stream>>>(Wac, Wat, Wrc, Wri, Wsc,
                                           Ec_f, Et_f, Erc_f, Erix_f, starts, ends, R);
    k2_find_bounds<<<(N + 255) / 256, 256, 0, stream>>>(ri, starts, ends, N);
    k3_fuse_prep<<<k3B, 256, 0, stream>>>(Ec_f, Et_f, Etab, starts, ends,
                                          rcode, rseq, acode, atype, rel, base,
                                          out_coords, hdr, recArr, R);
    k4_residue<<<1024, 256, 0, stream>>>(
        hdr, recArr, (const unsigned char*)Etab,
        Erc_f, Erix_f, Wv, acode, atype, rel, out_feat, R);
}